// Round 16
// baseline (640.007 us; speedup 1.0000x reference)
//
#include <hip/hip_runtime.h>
#include <math.h>

#define ED 128
// P layout: 8 channel-groups, each [n][32 f16] = 3.2 MB (fits one XCD L2).
// group g holds channels g*16..g*16+15 as interleaved {w,wv} half2.

typedef _Float16 f16;
typedef _Float16 half8 __attribute__((ext_vector_type(8)));
typedef _Float16 half4 __attribute__((ext_vector_type(4)));
typedef _Float16 half2v __attribute__((ext_vector_type(2)));
typedef float f32x4 __attribute__((ext_vector_type(4)));

// fast tanh: ~6 VALU ops via v_exp_f32; err ~1e-6
static __device__ __forceinline__ float tanh_fast(float x) {
  float ax = fabsf(x);
  float e = __expf(2.0f * ax);
  float t = 1.0f - 2.0f / (e + 1.0f);
  return __builtin_copysignf(t, x);
}

// ---- stage a [rows][256B] f16 weight panel into swizzled LDS ----
template <int NT, int NBYTES>
static __device__ __forceinline__ void stage256(
    const char* __restrict__ gsrc, char* lds, int tid) {
  #pragma unroll
  for (int i = 0; i < NBYTES / (NT * 16); ++i) {
    int b = (i * NT + tid) * 16;
    int row = b >> 8;
    int sw = (b & 255) ^ ((row & 7) << 4);
    float4 v = *reinterpret_cast<const float4*>(gsrc + (size_t)row * 256 + sw);
    *reinterpret_cast<float4*>(lds + b) = v;
  }
}

static __device__ __forceinline__ half8 read_w(const char* Wsb, int col, int koff) {
  int byte = col * 256 + (koff ^ ((col & 7) << 4));
  return *reinterpret_cast<const half8*>(Wsb + byte);
}

// ---- stage a [64 rows][512B] panel (uW col-half) into swizzled LDS ----
template <int NT>
static __device__ __forceinline__ void stage512(
    const char* __restrict__ gsrc, char* lds, int tid) {
  #pragma unroll
  for (int i = 0; i < 32768 / (NT * 16); ++i) {
    int b = (i * NT + tid) * 16;
    int row = b >> 9;
    int sw = (b & 511) ^ ((row & 7) << 4);
    float4 v = *reinterpret_cast<const float4*>(gsrc + (size_t)row * 512 + sw);
    *reinterpret_cast<float4*>(lds + b) = v;
  }
}

static __device__ __forceinline__ half8 read_w512(const char* Wsb, int colL, int koff) {
  int byte = colL * 512 + (koff ^ ((colL & 7) << 4));
  return *reinterpret_cast<const half8*>(Wsb + byte);
}

// ---------------- encoder: h = tanh(x @ enc_W + enc_b) -> f16 ----------------
__global__ __launch_bounds__(256) void encoder_kernel(
    const float* __restrict__ x, const float* __restrict__ W,
    const float* __restrict__ b, f16* __restrict__ h, int n) {
  int idx = blockIdx.x * blockDim.x + threadIdx.x;
  if (idx >= n * ED) return;
  int i = idx >> 7, c = idx & 127;
  float v = x[i * 2 + 0] * W[c] + x[i * 2 + 1] * W[ED + c] + b[c];
  h[idx] = (f16)tanh_fast(v);
}

// ---------------- weight transpose+cast ----------------
__global__ __launch_bounds__(256) void transpose_w_kernel(
    const float* __restrict__ src, f16* __restrict__ dst, int K, int C, int total) {
  int idx = blockIdx.x * 256 + threadIdx.x;
  if (idx >= total) return;
  int kc = K * C;
  int m = idx / kc;
  int rem = idx - m * kc;
  int c = rem / K;
  int k = rem - c * K;
  dst[idx] = (f16)src[(size_t)m * kc + (size_t)k * C + c];
}

__global__ __launch_bounds__(256) void transpose3_kernel(
    const float* __restrict__ s0, const float* __restrict__ s1,
    const float* __restrict__ s2, f16* __restrict__ d0,
    f16* __restrict__ d1, f16* __restrict__ d2) {
  int idx = blockIdx.x * 256 + threadIdx.x;
  const int per = 3 * 128 * 128;
  int which = idx / per;
  if (which >= 3) return;
  int rem = idx - which * per;
  const float* s = (which == 0) ? s0 : (which == 1) ? s1 : s2;
  f16* d = (which == 0) ? d0 : (which == 1) ? d1 : d2;
  int m = rem >> 14;
  int r2 = rem & 16383;
  int c = r2 >> 7, k = r2 & 127;
  d[rem] = (f16)s[m * 16384 + k * 128 + c];
}

// ---------------- CSR build ----------------
__global__ __launch_bounds__(256) void count_deg_kernel(
    const int* __restrict__ dst, int* __restrict__ deg, int E) {
  int e = blockIdx.x * blockDim.x + threadIdx.x;
  if (e < E) atomicAdd(&deg[dst[e]], 1);
}

__global__ __launch_bounds__(1024) void scan_kernel(
    const int* __restrict__ deg, int* __restrict__ offs,
    int* __restrict__ cursor, int n) {
  __shared__ int wsum[16];
  __shared__ int carry_s;
  const int tid = threadIdx.x;
  const int lane = tid & 63;
  const int wid = tid >> 6;
  if (tid == 0) carry_s = 0;
  __syncthreads();
  for (int base = 0; base < n; base += 1024) {
    const int i = base + tid;
    const int v = (i < n) ? deg[i] : 0;
    int x = v;
    #pragma unroll
    for (int d = 1; d < 64; d <<= 1) {
      int t = __shfl_up(x, d, 64);
      if (lane >= d) x += t;
    }
    if (lane == 63) wsum[wid] = x;
    __syncthreads();
    int wbase = 0, total = 0;
    #pragma unroll
    for (int w = 0; w < 16; ++w) {
      int s = wsum[w];
      if (w < wid) wbase += s;
      total += s;
    }
    const int carry = carry_s;
    if (i < n) {
      const int excl = carry + wbase + x - v;
      offs[i] = excl;
      cursor[i] = excl;
    }
    __syncthreads();
    if (tid == 0) carry_s = carry + total;
    __syncthreads();
  }
  if (tid == 0) offs[n] = carry_s;
}

__global__ __launch_bounds__(256) void scatter_kernel(
    const int* __restrict__ src, const int* __restrict__ dst,
    int* __restrict__ cursor, int* __restrict__ ssrc, int E) {
  int e = blockIdx.x * blockDim.x + threadIdx.x;
  if (e < E) {
    int d = dst[e];
    int pos = atomicAdd(&cursor[d], 1);
    ssrc[pos] = src[e];
  }
}

// ==================== GEMM kernels: 512 thr = 8 waves x 16-row stripes ======

// ---------------- MGV layer 0: phases M -> A(tq regs) -> G ----------------
__global__ __launch_bounds__(512, 4) void gemm_mgv_kernel(
    const f16* __restrict__ h,
    const f16* __restrict__ mWt, const float* __restrict__ mb,
    const f16* __restrict__ gWt, const float* __restrict__ gb,
    const f16* __restrict__ aWt, const float* __restrict__ ab,
    f16* __restrict__ P, int n) {
  __shared__ f16 Ws[128 * 128];
  __shared__ f16 Ss[128 * 128];
  char* Wsb = reinterpret_cast<char*>(Ws);
  char* Sb = reinterpret_cast<char*>(Ss);
  const int tid = threadIdx.x;
  const int wd = tid >> 6, lane = tid & 63;
  const int lr = lane & 15, lg = lane >> 4;
  const int r0 = blockIdx.x * 128 + wd * 16;
  const size_t gstride = (size_t)n * 32;

  half8 a[4];
  {
    int rr = r0 + lr;
    if (rr >= n) rr = n - 1;
    const f16* ap = h + (size_t)rr * ED + lg * 8;
    #pragma unroll
    for (int kt = 0; kt < 4; ++kt)
      a[kt] = *reinterpret_cast<const half8*>(ap + kt * 32);
  }

  // ---- phase M: M = tanh(h@mW+mb) -> stripe ----
  stage256<512, 32768>((const char*)mWt, Wsb, tid);
  __syncthreads();
  #pragma unroll
  for (int t = 0; t < 8; ++t) {
    f32x4 acc = {0.f, 0.f, 0.f, 0.f};
    int col = t * 16 + lr;
    #pragma unroll
    for (int kt = 0; kt < 4; ++kt)
      acc = __builtin_amdgcn_mfma_f32_16x16x32_f16(a[kt], read_w(Wsb, col, lg * 16 + kt * 64), acc, 0, 0, 0);
    float bias = mb[col];
    #pragma unroll
    for (int j = 0; j < 4; ++j) {
      int srow = wd * 16 + lg * 4 + j;
      int byte = srow * 256 + (((col * 2) ^ ((srow & 7) << 4)));
      *reinterpret_cast<f16*>(Sb + byte) = (f16)tanh_fast(acc[j] + bias);
    }
  }
  half8 ma[4];   // wave-private stripe rows
  {
    int lrow = wd * 16 + lr;
    #pragma unroll
    for (int kt = 0; kt < 4; ++kt) {
      int byte = lrow * 256 + ((lg * 16 + kt * 64) ^ ((lrow & 7) << 4));
      ma[kt] = *reinterpret_cast<const half8*>(Sb + byte);
    }
  }
  __syncthreads();

  // ---- phase A: tq = tanh(M@aW+ab) in registers ----
  stage256<512, 32768>((const char*)aWt, Wsb, tid);
  __syncthreads();
  half4 tq[8];
  #pragma unroll
  for (int t = 0; t < 8; ++t) {
    f32x4 acc = {0.f, 0.f, 0.f, 0.f};
    int col = t * 16 + lr;
    #pragma unroll
    for (int kt = 0; kt < 4; ++kt)
      acc = __builtin_amdgcn_mfma_f32_16x16x32_f16(ma[kt], read_w(Wsb, col, lg * 16 + kt * 64), acc, 0, 0, 0);
    float bias = ab[col];
    #pragma unroll
    for (int j = 0; j < 4; ++j) tq[t][j] = (f16)tanh_fast(acc[j] + bias);
  }
  __syncthreads();

  // ---- phase G: w = exp(M@gW+gb); Pg[t] row: {w,wv} half2 at chan lr ----
  stage256<512, 32768>((const char*)gWt, Wsb, tid);
  __syncthreads();
  #pragma unroll
  for (int t = 0; t < 8; ++t) {
    f32x4 acc = {0.f, 0.f, 0.f, 0.f};
    int col = t * 16 + lr;
    #pragma unroll
    for (int kt = 0; kt < 4; ++kt)
      acc = __builtin_amdgcn_mfma_f32_16x16x32_f16(ma[kt], read_w(Wsb, col, lg * 16 + kt * 64), acc, 0, 0, 0);
    float bias = gb[col];
    #pragma unroll
    for (int j = 0; j < 4; ++j) {
      int grow = r0 + lg * 4 + j;
      if (grow < n) {
        float wexp = fminf(__expf(acc[j] + bias), 60000.f);
        half2v pr;
        pr.x = (f16)wexp;
        pr.y = (f16)(wexp * (float)tq[t][j]);
        *reinterpret_cast<half2v*>(P + (size_t)t * gstride + (size_t)grow * 32 + lr * 2) = pr;
      }
    }
  }
}

// ---------------- fused upd + MGV (layers 1,2): U0,U1,M,A,G ----------------
__global__ __launch_bounds__(512, 4) void updmgv_kernel(
    const f16* __restrict__ h, const f16* __restrict__ ag,
    const f16* __restrict__ uWt, const float* __restrict__ ub,
    const f16* __restrict__ mWt, const float* __restrict__ mb,
    const f16* __restrict__ gWt, const float* __restrict__ gb,
    const f16* __restrict__ aWt, const float* __restrict__ ab,
    f16* __restrict__ hout, f16* __restrict__ P, int n) {
  __shared__ f16 Ws[128 * 128];
  __shared__ f16 Ss[128 * 128];
  char* Wsb = reinterpret_cast<char*>(Ws);
  char* Sb = reinterpret_cast<char*>(Ss);
  const int tid = threadIdx.x;
  const int wd = tid >> 6, lane = tid & 63;
  const int lr = lane & 15, lg = lane >> 4;
  const int r0 = blockIdx.x * 128 + wd * 16;
  const size_t gstride = (size_t)n * 32;

  half8 ah[4], aa[4];
  {
    int rr = r0 + lr;
    if (rr >= n) rr = n - 1;
    const f16* ap = h + (size_t)rr * ED + lg * 8;
    const f16* bp = ag + (size_t)rr * ED + lg * 8;
    #pragma unroll
    for (int kt = 0; kt < 4; ++kt) {
      ah[kt] = *reinterpret_cast<const half8*>(ap + kt * 32);
      aa[kt] = *reinterpret_cast<const half8*>(bp + kt * 32);
    }
  }

  // ---- phase U: h_new = tanh([h,ag]@uW+ub), split by COLUMN halves ----
  #pragma unroll
  for (int half = 0; half < 2; ++half) {
    __syncthreads();
    stage512<512>((const char*)uWt + (size_t)half * 64 * 512, Wsb, tid);
    __syncthreads();
    #pragma unroll
    for (int t = 0; t < 4; ++t) {
      int colL = t * 16 + lr;
      int col = half * 64 + colL;
      f32x4 acc = {0.f, 0.f, 0.f, 0.f};
      #pragma unroll
      for (int kt = 0; kt < 4; ++kt)
        acc = __builtin_amdgcn_mfma_f32_16x16x32_f16(ah[kt], read_w512(Wsb, colL, lg * 16 + kt * 64), acc, 0, 0, 0);
      #pragma unroll
      for (int kt = 0; kt < 4; ++kt)
        acc = __builtin_amdgcn_mfma_f32_16x16x32_f16(aa[kt], read_w512(Wsb, colL, 256 + lg * 16 + kt * 64), acc, 0, 0, 0);
      float bias = ub[col];
      #pragma unroll
      for (int j = 0; j < 4; ++j) {
        f16 hv = (f16)tanh_fast(acc[j] + bias);
        int srow = wd * 16 + lg * 4 + j;
        int byte = srow * 256 + (((col * 2) ^ ((srow & 7) << 4)));
        *reinterpret_cast<f16*>(Sb + byte) = hv;
        int grow = r0 + lg * 4 + j;
        if (grow < n) hout[(size_t)grow * ED + col] = hv;
      }
    }
  }
  half8 ha[4];
  {
    int lrow = wd * 16 + lr;
    #pragma unroll
    for (int kt = 0; kt < 4; ++kt) {
      int byte = lrow * 256 + ((lg * 16 + kt * 64) ^ ((lrow & 7) << 4));
      ha[kt] = *reinterpret_cast<const half8*>(Sb + byte);
    }
  }
  __syncthreads();

  // ---- phase M ----
  stage256<512, 32768>((const char*)mWt, Wsb, tid);
  __syncthreads();
  #pragma unroll
  for (int t = 0; t < 8; ++t) {
    f32x4 acc = {0.f, 0.f, 0.f, 0.f};
    int col = t * 16 + lr;
    #pragma unroll
    for (int kt = 0; kt < 4; ++kt)
      acc = __builtin_amdgcn_mfma_f32_16x16x32_f16(ha[kt], read_w(Wsb, col, lg * 16 + kt * 64), acc, 0, 0, 0);
    float bias = mb[col];
    #pragma unroll
    for (int j = 0; j < 4; ++j) {
      int srow = wd * 16 + lg * 4 + j;
      int byte = srow * 256 + (((col * 2) ^ ((srow & 7) << 4)));
      *reinterpret_cast<f16*>(Sb + byte) = (f16)tanh_fast(acc[j] + bias);
    }
  }
  half8 ma[4];
  {
    int lrow = wd * 16 + lr;
    #pragma unroll
    for (int kt = 0; kt < 4; ++kt) {
      int byte = lrow * 256 + ((lg * 16 + kt * 64) ^ ((lrow & 7) << 4));
      ma[kt] = *reinterpret_cast<const half8*>(Sb + byte);
    }
  }
  __syncthreads();

  // ---- phase A: tq in registers ----
  stage256<512, 32768>((const char*)aWt, Wsb, tid);
  __syncthreads();
  half4 tq[8];
  #pragma unroll
  for (int t = 0; t < 8; ++t) {
    f32x4 acc = {0.f, 0.f, 0.f, 0.f};
    int col = t * 16 + lr;
    #pragma unroll
    for (int kt = 0; kt < 4; ++kt)
      acc = __builtin_amdgcn_mfma_f32_16x16x32_f16(ma[kt], read_w(Wsb, col, lg * 16 + kt * 64), acc, 0, 0, 0);
    float bias = ab[col];
    #pragma unroll
    for (int j = 0; j < 4; ++j) tq[t][j] = (f16)tanh_fast(acc[j] + bias);
  }
  __syncthreads();

  // ---- phase G -> grouped P ----
  stage256<512, 32768>((const char*)gWt, Wsb, tid);
  __syncthreads();
  #pragma unroll
  for (int t = 0; t < 8; ++t) {
    f32x4 acc = {0.f, 0.f, 0.f, 0.f};
    int col = t * 16 + lr;
    #pragma unroll
    for (int kt = 0; kt < 4; ++kt)
      acc = __builtin_amdgcn_mfma_f32_16x16x32_f16(ma[kt], read_w(Wsb, col, lg * 16 + kt * 64), acc, 0, 0, 0);
    float bias = gb[col];
    #pragma unroll
    for (int j = 0; j < 4; ++j) {
      int grow = r0 + lg * 4 + j;
      if (grow < n) {
        float wexp = fminf(__expf(acc[j] + bias), 60000.f);
        half2v pr;
        pr.x = (f16)wexp;
        pr.y = (f16)(wexp * (float)tq[t][j]);
        *reinterpret_cast<half2v*>(P + (size_t)t * gstride + (size_t)grow * 32 + lr * 2) = pr;
      }
    }
  }
}

// ---------------- fused upd + decoder (layer 2 end) ----------------
__global__ __launch_bounds__(512, 4) void upddec_kernel(
    const f16* __restrict__ h, const f16* __restrict__ ag,
    const f16* __restrict__ uWt, const float* __restrict__ ub,
    const f16* __restrict__ d1Wt, const float* __restrict__ d1b,
    const float* __restrict__ d2W, const float* __restrict__ d2b,
    float* __restrict__ out, int n) {
  __shared__ f16 Ws[128 * 128];
  __shared__ f16 Ss[128 * 128];
  char* Wsb = reinterpret_cast<char*>(Ws);
  char* Sb = reinterpret_cast<char*>(Ss);
  const int tid = threadIdx.x;
  const int wd = tid >> 6, lane = tid & 63;
  const int lr = lane & 15, lg = lane >> 4;
  const int r0 = blockIdx.x * 128 + wd * 16;

  half8 ah[4], aa[4];
  {
    int rr = r0 + lr;
    if (rr >= n) rr = n - 1;
    const f16* ap = h + (size_t)rr * ED + lg * 8;
    const f16* bp = ag + (size_t)rr * ED + lg * 8;
    #pragma unroll
    for (int kt = 0; kt < 4; ++kt) {
      ah[kt] = *reinterpret_cast<const half8*>(ap + kt * 32);
      aa[kt] = *reinterpret_cast<const half8*>(bp + kt * 32);
    }
  }

  // ---- phase U (column halves) -> stripe only ----
  #pragma unroll
  for (int half = 0; half < 2; ++half) {
    __syncthreads();
    stage512<512>((const char*)uWt + (size_t)half * 64 * 512, Wsb, tid);
    __syncthreads();
    #pragma unroll
    for (int t = 0; t < 4; ++t) {
      int colL = t * 16 + lr;
      int col = half * 64 + colL;
      f32x4 acc = {0.f, 0.f, 0.f, 0.f};
      #pragma unroll
      for (int kt = 0; kt < 4; ++kt)
        acc = __builtin_amdgcn_mfma_f32_16x16x32_f16(ah[kt], read_w512(Wsb, colL, lg * 16 + kt * 64), acc, 0, 0, 0);
      #pragma unroll
      for (int kt = 0; kt < 4; ++kt)
        acc = __builtin_amdgcn_mfma_f32_16x16x32_f16(aa[kt], read_w512(Wsb, colL, 256 + lg * 16 + kt * 64), acc, 0, 0, 0);
      float bias = ub[col];
      #pragma unroll
      for (int j = 0; j < 4; ++j) {
        int srow = wd * 16 + lg * 4 + j;
        int byte = srow * 256 + (((col * 2) ^ ((srow & 7) << 4)));
        *reinterpret_cast<f16*>(Sb + byte) = (f16)tanh_fast(acc[j] + bias);
      }
    }
  }
  half8 ha[4];
  {
    int lrow = wd * 16 + lr;
    #pragma unroll
    for (int kt = 0; kt < 4; ++kt) {
      int byte = lrow * 256 + ((lg * 16 + kt * 64) ^ ((lrow & 7) << 4));
      ha[kt] = *reinterpret_cast<const half8*>(Sb + byte);
    }
  }
  __syncthreads();

  // ---- decoder ----
  stage256<512, 16384>((const char*)d1Wt, Wsb, tid);
  __syncthreads();
  float rowsum[4] = {0.f, 0.f, 0.f, 0.f};
  #pragma unroll
  for (int t = 0; t < 4; ++t) {
    f32x4 acc = {0.f, 0.f, 0.f, 0.f};
    int col = t * 16 + lr;
    #pragma unroll
    for (int kt = 0; kt < 4; ++kt)
      acc = __builtin_amdgcn_mfma_f32_16x16x32_f16(ha[kt], read_w(Wsb, col, lg * 16 + kt * 64), acc, 0, 0, 0);
    float b1 = d1b[col], w2 = d2W[col];
    #pragma unroll
    for (int j = 0; j < 4; ++j) rowsum[j] += tanh_fast(acc[j] + b1) * w2;
  }
  #pragma unroll
  for (int d = 1; d < 16; d <<= 1) {
    #pragma unroll
    for (int j = 0; j < 4; ++j) rowsum[j] += __shfl_xor(rowsum[j], d, 64);
  }
  if (lr == 0) {
    #pragma unroll
    for (int j = 0; j < 4; ++j) {
      int grow = r0 + lg * 4 + j;
      if (grow < n) out[grow] = rowsum[j] + d2b[0];
    }
  }
}

// ---------------- edge aggregation: XCD-localized, 1 wave = 1 node x 1 group
// lanes = 8 edge-slots x 8 channel-lanes; each lane loads half4 (2 {w,wv}
// pairs) -> 8 edges x 64B group-row per iteration (full-width loads, no
// divergence). Epilogue: 3 shfl_xor rounds over edge-slot axis.
__global__ __launch_bounds__(256) void edge_aggr_kernel(
    const int* __restrict__ offs, const int* __restrict__ ssrc,
    const f16* __restrict__ P, f16* __restrict__ aggr, int n) {
  int g = blockIdx.x & 7;
  int nb = blockIdx.x >> 3;
  int lane = threadIdx.x & 63;
  int es = lane >> 3;           // edge slot 0..7
  int cl = lane & 7;            // channel-pair lane (channels 2cl, 2cl+1)
  int node = nb * 4 + (threadIdx.x >> 6);
  if (node >= n) return;
  const f16* Pg = P + (size_t)g * (size_t)n * 32;
  int s0 = offs[node], s1 = offs[node + 1];

  float sw0 = 0.f, wv0 = 0.f, sw1 = 0.f, wv1 = 0.f;
  for (int e = s0 + es; e < s1; e += 8) {
    int sn = ssrc[e];
    half4 x = *reinterpret_cast<const half4*>(Pg + (size_t)sn * 32 + cl * 4);
    sw0 += (float)x.x;
    wv0 += (float)x.y;
    sw1 += (float)x.z;
    wv1 += (float)x.w;
  }
  // reduce across the 8 edge slots (lane bits 3,4,5)
  #pragma unroll
  for (int d = 8; d < 64; d <<= 1) {
    sw0 += __shfl_xor(sw0, d, 64);
    wv0 += __shfl_xor(wv0, d, 64);
    sw1 += __shfl_xor(sw1, d, 64);
    wv1 += __shfl_xor(wv1, d, 64);
  }
  if (es == 0) {
    half2v o;
    o.x = (f16)(wv0 / (sw0 + 1e-16f));
    o.y = (f16)(wv1 / (sw1 + 1e-16f));
    *reinterpret_cast<half2v*>(aggr + (size_t)node * ED + g * 16 + cl * 2) = o;
  }
}

// ---------------- host ----------------
extern "C" void kernel_launch(void* const* d_in, const int* in_sizes, int n_in,
                              void* d_out, int out_size, void* d_ws, size_t ws_size,
                              hipStream_t stream) {
  const float* node_feature = (const float*)d_in[0];
  const int*   edge_index   = (const int*)d_in[1];
  const float* enc_W  = (const float*)d_in[3];
  const float* enc_b  = (const float*)d_in[4];
  const float* gate_W = (const float*)d_in[5];
  const float* gate_b = (const float*)d_in[6];
  const float* att_W  = (const float*)d_in[7];
  const float* att_b  = (const float*)d_in[8];
  const float* msg_W  = (const float*)d_in[9];
  const float* msg_b  = (const float*)d_in[10];
  const float* upd_W  = (const float*)d_in[11];
  const float* upd_b  = (const float*)d_in[12];
  const float* dec1_W = (const float*)d_in[13];
  const float* dec1_b = (const float*)d_in[14];
  const float* dec2_W = (const float*)d_in[15];
  const float* dec2_b = (const float*)d_in[16];

  const int n = in_sizes[0] / 2;   // 50000
  const int E = in_sizes[1] / 2;   // 800000
  const int* src = edge_index;
  const int* dst = edge_index + E;

  char* ws = (char*)d_ws;
  size_t off = 0;
  auto alloc = [&](size_t bytes) -> void* {
    void* p = ws + off;
    off += (bytes + 255) & ~(size_t)255;
    return p;
  };
  f16* hA   = (f16*)alloc((size_t)n * ED * 2);
  f16* hB   = (f16*)alloc((size_t)n * ED * 2);
  f16* P    = (f16*)alloc((size_t)n * 256 * 2);   // 8 groups x [n][32 f16]
  f16* aggr = (f16*)alloc((size_t)n * ED * 2);
  int* deg    = (int*)alloc((size_t)n * 4);
  int* offs   = (int*)alloc((size_t)(n + 1) * 4);
  int* cursor = (int*)alloc((size_t)n * 4);
  int* ssrc   = (int*)alloc((size_t)E * 4);
  f16* msgT  = (f16*)alloc((size_t)3 * ED * ED * 2);
  f16* gateT = (f16*)alloc((size_t)3 * ED * ED * 2);
  f16* attT  = (f16*)alloc((size_t)3 * ED * ED * 2);
  f16* updT  = (f16*)alloc((size_t)3 * ED * 2 * ED * 2);
  f16* dec1T = (f16*)alloc((size_t)ED * 64 * 2);

  // weight prep (once per call)
  {
    int tot3 = 3 * 3 * ED * ED;
    transpose3_kernel<<<(tot3 + 255) / 256, 256, 0, stream>>>(
        msg_W, gate_W, att_W, msgT, gateT, attT);
    int totu = 3 * 2 * ED * ED;
    transpose_w_kernel<<<(totu + 255) / 256, 256, 0, stream>>>(
        upd_W, updT, 2 * ED, ED, totu);
    int totd = ED * 64;
    transpose_w_kernel<<<(totd + 255) / 256, 256, 0, stream>>>(
        dec1_W, dec1T, ED, 64, totd);
  }

  // CSR build (once per call)
  hipMemsetAsync(deg, 0, (size_t)n * 4, stream);
  count_deg_kernel<<<(E + 255) / 256, 256, 0, stream>>>(dst, deg, E);
  scan_kernel<<<1, 1024, 0, stream>>>(deg, offs, cursor, n);
  scatter_kernel<<<(E + 255) / 256, 256, 0, stream>>>(src, dst, cursor, ssrc, E);

  // encoder
  encoder_kernel<<<((size_t)n * ED + 255) / 256, 256, 0, stream>>>(
      node_feature, enc_W, enc_b, hA, n);

  const int gemm_grid = (n + 127) / 128;
  const int aggr_grid = ((n + 3) / 4) * 8;

  // layer 0 MGV
  gemm_mgv_kernel<<<gemm_grid, 512, 0, stream>>>(
      hA, msgT, msg_b, gateT, gate_b, attT, att_b, P, n);
  edge_aggr_kernel<<<aggr_grid, 256, 0, stream>>>(offs, ssrc, P, aggr, n);

  // upd0 + MGV1
  updmgv_kernel<<<gemm_grid, 512, 0, stream>>>(
      hA, aggr, updT, upd_b,
      msgT + (size_t)1 * ED * ED, msg_b + ED,
      gateT + (size_t)1 * ED * ED, gate_b + ED,
      attT + (size_t)1 * ED * ED, att_b + ED,
      hB, P, n);
  edge_aggr_kernel<<<aggr_grid, 256, 0, stream>>>(offs, ssrc, P, aggr, n);

  // upd1 + MGV2
  updmgv_kernel<<<gemm_grid, 512, 0, stream>>>(
      hB, aggr, updT + (size_t)1 * 2 * ED * ED, upd_b + ED,
      msgT + (size_t)2 * ED * ED, msg_b + 2 * ED,
      gateT + (size_t)2 * ED * ED, gate_b + 2 * ED,
      attT + (size_t)2 * ED * ED, att_b + 2 * ED,
      hA, P, n);
  edge_aggr_kernel<<<aggr_grid, 256, 0, stream>>>(offs, ssrc, P, aggr, n);

  // upd2 + decoder
  upddec_kernel<<<gemm_grid, 512, 0, stream>>>(
      hA, aggr, updT + (size_t)2 * 2 * ED * ED, upd_b + 2 * ED,
      dec1T, dec1_b, dec2_W, dec2_b, (float*)d_out, n);
}

// Round 17
// 453.295 us; speedup vs baseline: 1.4119x; 1.4119x over previous
//
#include <hip/hip_runtime.h>
#include <math.h>

#define ED 128
// packed per-node row: 128 f16 w=exp(gate) + 128 f16 wv=w*v  (512 B)
#define PROW 256

typedef _Float16 f16;
typedef _Float16 half8 __attribute__((ext_vector_type(8)));
typedef _Float16 half4 __attribute__((ext_vector_type(4)));
typedef float f32x4 __attribute__((ext_vector_type(4)));

// fast tanh: ~6 VALU ops via v_exp_f32; err ~1e-6
static __device__ __forceinline__ float tanh_fast(float x) {
  float ax = fabsf(x);
  float e = __expf(2.0f * ax);
  float t = 1.0f - 2.0f / (e + 1.0f);
  return __builtin_copysignf(t, x);
}

// ---- stage a [rows][256B] f16 weight panel into swizzled LDS ----
template <int NT, int NBYTES>
static __device__ __forceinline__ void stage256(
    const char* __restrict__ gsrc, char* lds, int tid) {
  #pragma unroll
  for (int i = 0; i < NBYTES / (NT * 16); ++i) {
    int b = (i * NT + tid) * 16;
    int row = b >> 8;
    int sw = (b & 255) ^ ((row & 7) << 4);
    float4 v = *reinterpret_cast<const float4*>(gsrc + (size_t)row * 256 + sw);
    *reinterpret_cast<float4*>(lds + b) = v;
  }
}

static __device__ __forceinline__ half8 read_w(const char* Wsb, int col, int koff) {
  int byte = col * 256 + (koff ^ ((col & 7) << 4));
  return *reinterpret_cast<const half8*>(Wsb + byte);
}

// ---- stage a [64 rows][512B] panel (uW col-half) into swizzled LDS ----
template <int NT>
static __device__ __forceinline__ void stage512(
    const char* __restrict__ gsrc, char* lds, int tid) {
  #pragma unroll
  for (int i = 0; i < 32768 / (NT * 16); ++i) {
    int b = (i * NT + tid) * 16;
    int row = b >> 9;
    int sw = (b & 511) ^ ((row & 7) << 4);
    float4 v = *reinterpret_cast<const float4*>(gsrc + (size_t)row * 512 + sw);
    *reinterpret_cast<float4*>(lds + b) = v;
  }
}

static __device__ __forceinline__ half8 read_w512(const char* Wsb, int colL, int koff) {
  int byte = colL * 512 + (koff ^ ((colL & 7) << 4));
  return *reinterpret_cast<const half8*>(Wsb + byte);
}

// ---------------- encoder: h = tanh(x @ enc_W + enc_b) -> f16 ----------------
__global__ __launch_bounds__(256) void encoder_kernel(
    const float* __restrict__ x, const float* __restrict__ W,
    const float* __restrict__ b, f16* __restrict__ h, int n) {
  int idx = blockIdx.x * blockDim.x + threadIdx.x;
  if (idx >= n * ED) return;
  int i = idx >> 7, c = idx & 127;
  float v = x[i * 2 + 0] * W[c] + x[i * 2 + 1] * W[ED + c] + b[c];
  h[idx] = (f16)tanh_fast(v);
}

// ---------------- weight transpose+cast ----------------
__global__ __launch_bounds__(256) void transpose_w_kernel(
    const float* __restrict__ src, f16* __restrict__ dst, int K, int C, int total) {
  int idx = blockIdx.x * 256 + threadIdx.x;
  if (idx >= total) return;
  int kc = K * C;
  int m = idx / kc;
  int rem = idx - m * kc;
  int c = rem / K;
  int k = rem - c * K;
  dst[idx] = (f16)src[(size_t)m * kc + (size_t)k * C + c];
}

__global__ __launch_bounds__(256) void transpose3_kernel(
    const float* __restrict__ s0, const float* __restrict__ s1,
    const float* __restrict__ s2, f16* __restrict__ d0,
    f16* __restrict__ d1, f16* __restrict__ d2) {
  int idx = blockIdx.x * 256 + threadIdx.x;
  const int per = 3 * 128 * 128;
  int which = idx / per;
  if (which >= 3) return;
  int rem = idx - which * per;
  const float* s = (which == 0) ? s0 : (which == 1) ? s1 : s2;
  f16* d = (which == 0) ? d0 : (which == 1) ? d1 : d2;
  int m = rem >> 14;
  int r2 = rem & 16383;
  int c = r2 >> 7, k = r2 & 127;
  d[rem] = (f16)s[m * 16384 + k * 128 + c];
}

// ---------------- CSR build ----------------
__global__ __launch_bounds__(256) void count_deg_kernel(
    const int* __restrict__ dst, int* __restrict__ deg, int E) {
  int e = blockIdx.x * blockDim.x + threadIdx.x;
  if (e < E) atomicAdd(&deg[dst[e]], 1);
}

__global__ __launch_bounds__(1024) void scan_kernel(
    const int* __restrict__ deg, int* __restrict__ offs,
    int* __restrict__ cursor, int n) {
  __shared__ int wsum[16];
  __shared__ int carry_s;
  const int tid = threadIdx.x;
  const int lane = tid & 63;
  const int wid = tid >> 6;
  if (tid == 0) carry_s = 0;
  __syncthreads();
  for (int base = 0; base < n; base += 1024) {
    const int i = base + tid;
    const int v = (i < n) ? deg[i] : 0;
    int x = v;
    #pragma unroll
    for (int d = 1; d < 64; d <<= 1) {
      int t = __shfl_up(x, d, 64);
      if (lane >= d) x += t;
    }
    if (lane == 63) wsum[wid] = x;
    __syncthreads();
    int wbase = 0, total = 0;
    #pragma unroll
    for (int w = 0; w < 16; ++w) {
      int s = wsum[w];
      if (w < wid) wbase += s;
      total += s;
    }
    const int carry = carry_s;
    if (i < n) {
      const int excl = carry + wbase + x - v;
      offs[i] = excl;
      cursor[i] = excl;
    }
    __syncthreads();
    if (tid == 0) carry_s = carry + total;
    __syncthreads();
  }
  if (tid == 0) offs[n] = carry_s;
}

__global__ __launch_bounds__(256) void scatter_kernel(
    const int* __restrict__ src, const int* __restrict__ dst,
    int* __restrict__ cursor, int* __restrict__ ssrc, int E) {
  int e = blockIdx.x * blockDim.x + threadIdx.x;
  if (e < E) {
    int d = dst[e];
    int pos = atomicAdd(&cursor[d], 1);
    ssrc[pos] = src[e];
  }
}

// ==================== GEMM kernels: 512 thr = 8 waves x 16-row stripes,
// 128 rows/block (grid 391), weights staged in swizzled LDS per phase ========

// ---------------- MGV layer 0 ----------------
__global__ __launch_bounds__(512, 4) void gemm_mgv_kernel(
    const f16* __restrict__ h,
    const f16* __restrict__ mWt, const float* __restrict__ mb,
    const f16* __restrict__ gWt, const float* __restrict__ gb,
    const f16* __restrict__ aWt, const float* __restrict__ ab,
    f16* __restrict__ P, int n) {
  __shared__ f16 Ws[128 * 128];   // 32 KB weight panel
  __shared__ f16 Ss[128 * 128];   // 32 KB stripe buffer (M)
  char* Wsb = reinterpret_cast<char*>(Ws);
  char* Sb = reinterpret_cast<char*>(Ss);
  const int tid = threadIdx.x;
  const int w = tid >> 6, lane = tid & 63;
  const int lr = lane & 15, lg = lane >> 4;
  const int r0 = blockIdx.x * 128 + w * 16;

  half8 a[4];
  {
    int rr = r0 + lr;
    if (rr >= n) rr = n - 1;
    const f16* ap = h + (size_t)rr * ED + lg * 8;
    #pragma unroll
    for (int kt = 0; kt < 4; ++kt)
      a[kt] = *reinterpret_cast<const half8*>(ap + kt * 32);
  }

  // ---- phase M: M = tanh(h@mW+mb) -> stripe ----
  stage256<512, 32768>((const char*)mWt, Wsb, tid);
  __syncthreads();
  #pragma unroll
  for (int t = 0; t < 8; ++t) {
    f32x4 acc = {0.f, 0.f, 0.f, 0.f};
    int col = t * 16 + lr;
    #pragma unroll
    for (int kt = 0; kt < 4; ++kt)
      acc = __builtin_amdgcn_mfma_f32_16x16x32_f16(a[kt], read_w(Wsb, col, lg * 16 + kt * 64), acc, 0, 0, 0);
    float bias = mb[col];
    #pragma unroll
    for (int j = 0; j < 4; ++j) {
      int srow = w * 16 + lg * 4 + j;
      int byte = srow * 256 + (((col * 2) ^ ((srow & 7) << 4)));
      *reinterpret_cast<f16*>(Sb + byte) = (f16)tanh_fast(acc[j] + bias);
    }
  }
  half8 ma[4];   // wave-local stripe read (own rows) — no barrier needed
  {
    int lrow = w * 16 + lr;
    #pragma unroll
    for (int kt = 0; kt < 4; ++kt) {
      int byte = lrow * 256 + ((lg * 16 + kt * 64) ^ ((lrow & 7) << 4));
      ma[kt] = *reinterpret_cast<const half8*>(Sb + byte);
    }
  }
  __syncthreads();

  // ---- phase G: w = exp(M@gW+gb) -> P ----
  stage256<512, 32768>((const char*)gWt, Wsb, tid);
  __syncthreads();
  #pragma unroll
  for (int t = 0; t < 8; ++t) {
    f32x4 acc = {0.f, 0.f, 0.f, 0.f};
    int col = t * 16 + lr;
    #pragma unroll
    for (int kt = 0; kt < 4; ++kt)
      acc = __builtin_amdgcn_mfma_f32_16x16x32_f16(ma[kt], read_w(Wsb, col, lg * 16 + kt * 64), acc, 0, 0, 0);
    float bias = gb[col];
    #pragma unroll
    for (int j = 0; j < 4; ++j) {
      int grow = r0 + lg * 4 + j;
      if (grow < n)
        P[(size_t)grow * PROW + col] = (f16)fminf(__expf(acc[j] + bias), 60000.f);
    }
  }
  __syncthreads();

  // ---- phase V: wv = w * tanh(M@aW+ab); w re-read from P (same thread wrote it)
  stage256<512, 32768>((const char*)aWt, Wsb, tid);
  __syncthreads();
  #pragma unroll
  for (int t = 0; t < 8; ++t) {
    f32x4 acc = {0.f, 0.f, 0.f, 0.f};
    int col = t * 16 + lr;
    #pragma unroll
    for (int kt = 0; kt < 4; ++kt)
      acc = __builtin_amdgcn_mfma_f32_16x16x32_f16(ma[kt], read_w(Wsb, col, lg * 16 + kt * 64), acc, 0, 0, 0);
    float bias = ab[col];
    #pragma unroll
    for (int j = 0; j < 4; ++j) {
      int grow = r0 + lg * 4 + j;
      if (grow < n) {
        float wld = (float)P[(size_t)grow * PROW + col];
        P[(size_t)grow * PROW + 128 + col] = (f16)(wld * tanh_fast(acc[j] + bias));
      }
    }
  }
}

// ---------------- fused upd + MGV (layers 1,2) ----------------
__global__ __launch_bounds__(512, 4) void updmgv_kernel(
    const f16* __restrict__ h, const f16* __restrict__ ag,
    const f16* __restrict__ uWt, const float* __restrict__ ub,
    const f16* __restrict__ mWt, const float* __restrict__ mb,
    const f16* __restrict__ gWt, const float* __restrict__ gb,
    const f16* __restrict__ aWt, const float* __restrict__ ab,
    f16* __restrict__ hout, f16* __restrict__ P, int n) {
  __shared__ f16 Ws[128 * 128];   // 32 KB weight panel
  __shared__ f16 Ss[128 * 128];   // 32 KB stripe buffer (h_new, then M)
  char* Wsb = reinterpret_cast<char*>(Ws);
  char* Sb = reinterpret_cast<char*>(Ss);
  const int tid = threadIdx.x;
  const int w = tid >> 6, lane = tid & 63;
  const int lr = lane & 15, lg = lane >> 4;
  const int r0 = blockIdx.x * 128 + w * 16;

  half8 ah[4], aa[4];
  {
    int rr = r0 + lr;
    if (rr >= n) rr = n - 1;
    const f16* ap = h + (size_t)rr * ED + lg * 8;
    const f16* bp = ag + (size_t)rr * ED + lg * 8;
    #pragma unroll
    for (int kt = 0; kt < 4; ++kt) {
      ah[kt] = *reinterpret_cast<const half8*>(ap + kt * 32);
      aa[kt] = *reinterpret_cast<const half8*>(bp + kt * 32);
    }
  }

  // ---- phase U: h_new = tanh([h,ag]@uW+ub), split by COLUMN halves ----
  #pragma unroll
  for (int half = 0; half < 2; ++half) {
    __syncthreads();   // prior readers of Ws done (no-op on first iter)
    stage512<512>((const char*)uWt + (size_t)half * 64 * 512, Wsb, tid);
    __syncthreads();
    #pragma unroll
    for (int t = 0; t < 4; ++t) {
      int colL = t * 16 + lr;
      int col = half * 64 + colL;
      f32x4 acc = {0.f, 0.f, 0.f, 0.f};
      #pragma unroll
      for (int kt = 0; kt < 4; ++kt)
        acc = __builtin_amdgcn_mfma_f32_16x16x32_f16(ah[kt], read_w512(Wsb, colL, lg * 16 + kt * 64), acc, 0, 0, 0);
      #pragma unroll
      for (int kt = 0; kt < 4; ++kt)
        acc = __builtin_amdgcn_mfma_f32_16x16x32_f16(aa[kt], read_w512(Wsb, colL, 256 + lg * 16 + kt * 64), acc, 0, 0, 0);
      float bias = ub[col];
      #pragma unroll
      for (int j = 0; j < 4; ++j) {
        f16 hv = (f16)tanh_fast(acc[j] + bias);
        int srow = w * 16 + lg * 4 + j;
        int byte = srow * 256 + (((col * 2) ^ ((srow & 7) << 4)));
        *reinterpret_cast<f16*>(Sb + byte) = hv;
        int grow = r0 + lg * 4 + j;
        if (grow < n) hout[(size_t)grow * ED + col] = hv;
      }
    }
  }
  half8 ha[4];   // wave-local stripe read
  {
    int lrow = w * 16 + lr;
    #pragma unroll
    for (int kt = 0; kt < 4; ++kt) {
      int byte = lrow * 256 + ((lg * 16 + kt * 64) ^ ((lrow & 7) << 4));
      ha[kt] = *reinterpret_cast<const half8*>(Sb + byte);
    }
  }
  __syncthreads();

  // ---- phase M ----
  stage256<512, 32768>((const char*)mWt, Wsb, tid);
  __syncthreads();
  #pragma unroll
  for (int t = 0; t < 8; ++t) {
    f32x4 acc = {0.f, 0.f, 0.f, 0.f};
    int col = t * 16 + lr;
    #pragma unroll
    for (int kt = 0; kt < 4; ++kt)
      acc = __builtin_amdgcn_mfma_f32_16x16x32_f16(ha[kt], read_w(Wsb, col, lg * 16 + kt * 64), acc, 0, 0, 0);
    float bias = mb[col];
    #pragma unroll
    for (int j = 0; j < 4; ++j) {
      int srow = w * 16 + lg * 4 + j;
      int byte = srow * 256 + (((col * 2) ^ ((srow & 7) << 4)));
      *reinterpret_cast<f16*>(Sb + byte) = (f16)tanh_fast(acc[j] + bias);
    }
  }
  half8 ma[4];
  {
    int lrow = w * 16 + lr;
    #pragma unroll
    for (int kt = 0; kt < 4; ++kt) {
      int byte = lrow * 256 + ((lg * 16 + kt * 64) ^ ((lrow & 7) << 4));
      ma[kt] = *reinterpret_cast<const half8*>(Sb + byte);
    }
  }
  __syncthreads();

  // ---- phase G ----
  stage256<512, 32768>((const char*)gWt, Wsb, tid);
  __syncthreads();
  #pragma unroll
  for (int t = 0; t < 8; ++t) {
    f32x4 acc = {0.f, 0.f, 0.f, 0.f};
    int col = t * 16 + lr;
    #pragma unroll
    for (int kt = 0; kt < 4; ++kt)
      acc = __builtin_amdgcn_mfma_f32_16x16x32_f16(ma[kt], read_w(Wsb, col, lg * 16 + kt * 64), acc, 0, 0, 0);
    float bias = gb[col];
    #pragma unroll
    for (int j = 0; j < 4; ++j) {
      int grow = r0 + lg * 4 + j;
      if (grow < n)
        P[(size_t)grow * PROW + col] = (f16)fminf(__expf(acc[j] + bias), 60000.f);
    }
  }
  __syncthreads();

  // ---- phase V (w re-read from P) ----
  stage256<512, 32768>((const char*)aWt, Wsb, tid);
  __syncthreads();
  #pragma unroll
  for (int t = 0; t < 8; ++t) {
    f32x4 acc = {0.f, 0.f, 0.f, 0.f};
    int col = t * 16 + lr;
    #pragma unroll
    for (int kt = 0; kt < 4; ++kt)
      acc = __builtin_amdgcn_mfma_f32_16x16x32_f16(ma[kt], read_w(Wsb, col, lg * 16 + kt * 64), acc, 0, 0, 0);
    float bias = ab[col];
    #pragma unroll
    for (int j = 0; j < 4; ++j) {
      int grow = r0 + lg * 4 + j;
      if (grow < n) {
        float wld = (float)P[(size_t)grow * PROW + col];
        P[(size_t)grow * PROW + 128 + col] = (f16)(wld * tanh_fast(acc[j] + bias));
      }
    }
  }
}

// ---------------- fused upd + decoder (layer 2 end) ----------------
__global__ __launch_bounds__(512, 4) void upddec_kernel(
    const f16* __restrict__ h, const f16* __restrict__ ag,
    const f16* __restrict__ uWt, const float* __restrict__ ub,
    const f16* __restrict__ d1Wt, const float* __restrict__ d1b,
    const float* __restrict__ d2W, const float* __restrict__ d2b,
    float* __restrict__ out, int n) {
  __shared__ f16 Ws[128 * 128];
  __shared__ f16 Ss[128 * 128];
  char* Wsb = reinterpret_cast<char*>(Ws);
  char* Sb = reinterpret_cast<char*>(Ss);
  const int tid = threadIdx.x;
  const int w = tid >> 6, lane = tid & 63;
  const int lr = lane & 15, lg = lane >> 4;
  const int r0 = blockIdx.x * 128 + w * 16;

  half8 ah[4], aa[4];
  {
    int rr = r0 + lr;
    if (rr >= n) rr = n - 1;
    const f16* ap = h + (size_t)rr * ED + lg * 8;
    const f16* bp = ag + (size_t)rr * ED + lg * 8;
    #pragma unroll
    for (int kt = 0; kt < 4; ++kt) {
      ah[kt] = *reinterpret_cast<const half8*>(ap + kt * 32);
      aa[kt] = *reinterpret_cast<const half8*>(bp + kt * 32);
    }
  }

  // ---- phase U (column halves) -> stripe only ----
  #pragma unroll
  for (int half = 0; half < 2; ++half) {
    __syncthreads();
    stage512<512>((const char*)uWt + (size_t)half * 64 * 512, Wsb, tid);
    __syncthreads();
    #pragma unroll
    for (int t = 0; t < 4; ++t) {
      int colL = t * 16 + lr;
      int col = half * 64 + colL;
      f32x4 acc = {0.f, 0.f, 0.f, 0.f};
      #pragma unroll
      for (int kt = 0; kt < 4; ++kt)
        acc = __builtin_amdgcn_mfma_f32_16x16x32_f16(ah[kt], read_w512(Wsb, colL, lg * 16 + kt * 64), acc, 0, 0, 0);
      #pragma unroll
      for (int kt = 0; kt < 4; ++kt)
        acc = __builtin_amdgcn_mfma_f32_16x16x32_f16(aa[kt], read_w512(Wsb, colL, 256 + lg * 16 + kt * 64), acc, 0, 0, 0);
      float bias = ub[col];
      #pragma unroll
      for (int j = 0; j < 4; ++j) {
        int srow = w * 16 + lg * 4 + j;
        int byte = srow * 256 + (((col * 2) ^ ((srow & 7) << 4)));
        *reinterpret_cast<f16*>(Sb + byte) = (f16)tanh_fast(acc[j] + bias);
      }
    }
  }
  half8 ha[4];
  {
    int lrow = w * 16 + lr;
    #pragma unroll
    for (int kt = 0; kt < 4; ++kt) {
      int byte = lrow * 256 + ((lg * 16 + kt * 64) ^ ((lrow & 7) << 4));
      ha[kt] = *reinterpret_cast<const half8*>(Sb + byte);
    }
  }
  __syncthreads();

  // ---- decoder: y = tanh(h3@d1W+d1b); out = y@d2W + d2b ----
  stage256<512, 16384>((const char*)d1Wt, Wsb, tid);   // 64 cols x 128 k
  __syncthreads();
  float rowsum[4] = {0.f, 0.f, 0.f, 0.f};
  #pragma unroll
  for (int t = 0; t < 4; ++t) {
    f32x4 acc = {0.f, 0.f, 0.f, 0.f};
    int col = t * 16 + lr;
    #pragma unroll
    for (int kt = 0; kt < 4; ++kt)
      acc = __builtin_amdgcn_mfma_f32_16x16x32_f16(ha[kt], read_w(Wsb, col, lg * 16 + kt * 64), acc, 0, 0, 0);
    float b1 = d1b[col], w2 = d2W[col];
    #pragma unroll
    for (int j = 0; j < 4; ++j) rowsum[j] += tanh_fast(acc[j] + b1) * w2;
  }
  #pragma unroll
  for (int d = 1; d < 16; d <<= 1) {
    #pragma unroll
    for (int j = 0; j < 4; ++j) rowsum[j] += __shfl_xor(rowsum[j], d, 64);
  }
  if (lr == 0) {
    #pragma unroll
    for (int j = 0; j < 4; ++j) {
      int grow = r0 + lg * 4 + j;
      if (grow < n) out[grow] = rowsum[j] + d2b[0];
    }
  }
}

// ---------------- edge aggregation: one wave per dst node, pure gather-sum ---
// (proven 54.4 us / 3.4 TB/s — the random-gather floor for this op)
__global__ __launch_bounds__(256) void edge_aggr_kernel(
    const int* __restrict__ offs, const int* __restrict__ ssrc,
    const f16* __restrict__ P, f16* __restrict__ aggr, int n) {
  int i = blockIdx.x * 4 + (threadIdx.x >> 6);
  if (i >= n) return;
  int lane = threadIdx.x & 63;
  int s0 = offs[i], s1 = offs[i + 1];
  const char* Pb = reinterpret_cast<const char*>(P);

  float4 acc = {0.f, 0.f, 0.f, 0.f};
  #pragma unroll 4
  for (int e = s0; e < s1; ++e) {
    int sn = ssrc[e];
    half4 x = *reinterpret_cast<const half4*>(Pb + (size_t)sn * 512 + lane * 8);
    acc.x += (float)x.x;
    acc.y += (float)x.y;
    acc.z += (float)x.z;
    acc.w += (float)x.w;
  }
  float px = __shfl(acc.x, lane ^ 32, 64);
  float py = __shfl(acc.y, lane ^ 32, 64);
  float pz = __shfl(acc.z, lane ^ 32, 64);
  float pw = __shfl(acc.w, lane ^ 32, 64);
  if (lane >= 32) {
    half4 o;
    o.x = (f16)(acc.x / (px + 1e-16f));
    o.y = (f16)(acc.y / (py + 1e-16f));
    o.z = (f16)(acc.z / (pz + 1e-16f));
    o.w = (f16)(acc.w / (pw + 1e-16f));
    *reinterpret_cast<half4*>(
        reinterpret_cast<char*>(aggr) + (size_t)i * 256 + (size_t)(lane - 32) * 8) = o;
  }
}

// ---------------- host ----------------
extern "C" void kernel_launch(void* const* d_in, const int* in_sizes, int n_in,
                              void* d_out, int out_size, void* d_ws, size_t ws_size,
                              hipStream_t stream) {
  const float* node_feature = (const float*)d_in[0];
  const int*   edge_index   = (const int*)d_in[1];
  const float* enc_W  = (const float*)d_in[3];
  const float* enc_b  = (const float*)d_in[4];
  const float* gate_W = (const float*)d_in[5];
  const float* gate_b = (const float*)d_in[6];
  const float* att_W  = (const float*)d_in[7];
  const float* att_b  = (const float*)d_in[8];
  const float* msg_W  = (const float*)d_in[9];
  const float* msg_b  = (const float*)d_in[10];
  const float* upd_W  = (const float*)d_in[11];
  const float* upd_b  = (const float*)d_in[12];
  const float* dec1_W = (const float*)d_in[13];
  const float* dec1_b = (const float*)d_in[14];
  const float* dec2_W = (const float*)d_in[15];
  const float* dec2_b = (const float*)d_in[16];

  const int n = in_sizes[0] / 2;   // 50000
  const int E = in_sizes[1] / 2;   // 800000
  const int* src = edge_index;
  const int* dst = edge_index + E;

  char* ws = (char*)d_ws;
  size_t off = 0;
  auto alloc = [&](size_t bytes) -> void* {
    void* p = ws + off;
    off += (bytes + 255) & ~(size_t)255;
    return p;
  };
  f16* hA   = (f16*)alloc((size_t)n * ED * 2);
  f16* hB   = (f16*)alloc((size_t)n * ED * 2);
  f16* P    = (f16*)alloc((size_t)n * PROW * 2);
  f16* aggr = (f16*)alloc((size_t)n * ED * 2);
  int* deg    = (int*)alloc((size_t)n * 4);
  int* offs   = (int*)alloc((size_t)(n + 1) * 4);
  int* cursor = (int*)alloc((size_t)n * 4);
  int* ssrc   = (int*)alloc((size_t)E * 4);
  f16* msgT  = (f16*)alloc((size_t)3 * ED * ED * 2);
  f16* gateT = (f16*)alloc((size_t)3 * ED * ED * 2);
  f16* attT  = (f16*)alloc((size_t)3 * ED * ED * 2);
  f16* updT  = (f16*)alloc((size_t)3 * ED * 2 * ED * 2);
  f16* dec1T = (f16*)alloc((size_t)ED * 64 * 2);

  // weight prep (once per call)
  {
    int tot3 = 3 * 3 * ED * ED;
    transpose3_kernel<<<(tot3 + 255) / 256, 256, 0, stream>>>(
        msg_W, gate_W, att_W, msgT, gateT, attT);
    int totu = 3 * 2 * ED * ED;
    transpose_w_kernel<<<(totu + 255) / 256, 256, 0, stream>>>(
        upd_W, updT, 2 * ED, ED, totu);
    int totd = ED * 64;
    transpose_w_kernel<<<(totd + 255) / 256, 256, 0, stream>>>(
        dec1_W, dec1T, ED, 64, totd);
  }

  // CSR build (once per call)
  hipMemsetAsync(deg, 0, (size_t)n * 4, stream);
  count_deg_kernel<<<(E + 255) / 256, 256, 0, stream>>>(dst, deg, E);
  scan_kernel<<<1, 1024, 0, stream>>>(deg, offs, cursor, n);
  scatter_kernel<<<(E + 255) / 256, 256, 0, stream>>>(src, dst, cursor, ssrc, E);

  // encoder
  encoder_kernel<<<((size_t)n * ED + 255) / 256, 256, 0, stream>>>(
      node_feature, enc_W, enc_b, hA, n);

  const int gemm_grid = (n + 127) / 128;   // 512-thread blocks, 128 rows
  const int aggr_grid = (n + 3) / 4;

  // layer 0 MGV
  gemm_mgv_kernel<<<gemm_grid, 512, 0, stream>>>(
      hA, msgT, msg_b, gateT, gate_b, attT, att_b, P, n);
  edge_aggr_kernel<<<aggr_grid, 256, 0, stream>>>(offs, ssrc, P, aggr, n);

  // upd0 + MGV1
  updmgv_kernel<<<gemm_grid, 512, 0, stream>>>(
      hA, aggr, updT, upd_b,
      msgT + (size_t)1 * ED * ED, msg_b + ED,
      gateT + (size_t)1 * ED * ED, gate_b + ED,
      attT + (size_t)1 * ED * ED, att_b + ED,
      hB, P, n);
  edge_aggr_kernel<<<aggr_grid, 256, 0, stream>>>(offs, ssrc, P, aggr, n);

  // upd1 + MGV2
  updmgv_kernel<<<gemm_grid, 512, 0, stream>>>(
      hB, aggr, updT + (size_t)1 * 2 * ED * ED, upd_b + ED,
      msgT + (size_t)2 * ED * ED, msg_b + 2 * ED,
      gateT + (size_t)2 * ED * ED, gate_b + 2 * ED,
      attT + (size_t)2 * ED * ED, att_b + 2 * ED,
      hA, P, n);
  edge_aggr_kernel<<<aggr_grid, 256, 0, stream>>>(offs, ssrc, P, aggr, n);

  // upd2 + decoder
  upddec_kernel<<<gemm_grid, 512, 0, stream>>>(
      hA, aggr, updT + (size_t)2 * 2 * ED * ED, upd_b + 2 * ED,
      dec1T, dec1_b, dec2_W, dec2_b, (float*)d_out, n);
}

// Round 18
// 417.525 us; speedup vs baseline: 1.5329x; 1.0857x over previous
//
#include <hip/hip_runtime.h>
#include <math.h>

#define ED 128
// packed per-node row: 128 f16 w=exp(gate) + 128 f16 wv=w*v  (512 B)
#define PROW 256

typedef _Float16 f16;
typedef _Float16 half8 __attribute__((ext_vector_type(8)));
typedef _Float16 half4 __attribute__((ext_vector_type(4)));
typedef float f32x4 __attribute__((ext_vector_type(4)));

// fast tanh: ~6 VALU ops via v_exp_f32; err ~1e-6
static __device__ __forceinline__ float tanh_fast(float x) {
  float ax = fabsf(x);
  float e = __expf(2.0f * ax);
  float t = 1.0f - 2.0f / (e + 1.0f);
  return __builtin_copysignf(t, x);
}

// ---- stage a [rows][256B] f16 weight panel into swizzled LDS ----
template <int NT, int NBYTES>
static __device__ __forceinline__ void stage256(
    const char* __restrict__ gsrc, char* lds, int tid) {
  #pragma unroll
  for (int i = 0; i < NBYTES / (NT * 16); ++i) {
    int b = (i * NT + tid) * 16;
    int row = b >> 8;
    int sw = (b & 255) ^ ((row & 7) << 4);
    float4 v = *reinterpret_cast<const float4*>(gsrc + (size_t)row * 256 + sw);
    *reinterpret_cast<float4*>(lds + b) = v;
  }
}

static __device__ __forceinline__ half8 read_w(const char* Wsb, int col, int koff) {
  int byte = col * 256 + (koff ^ ((col & 7) << 4));
  return *reinterpret_cast<const half8*>(Wsb + byte);
}

// ---- stage a [64 rows][512B] panel (uW col-half) into swizzled LDS ----
template <int NT>
static __device__ __forceinline__ void stage512(
    const char* __restrict__ gsrc, char* lds, int tid) {
  #pragma unroll
  for (int i = 0; i < 32768 / (NT * 16); ++i) {
    int b = (i * NT + tid) * 16;
    int row = b >> 9;
    int sw = (b & 511) ^ ((row & 7) << 4);
    float4 v = *reinterpret_cast<const float4*>(gsrc + (size_t)row * 512 + sw);
    *reinterpret_cast<float4*>(lds + b) = v;
  }
}

static __device__ __forceinline__ half8 read_w512(const char* Wsb, int colL, int koff) {
  int byte = colL * 512 + (koff ^ ((colL & 7) << 4));
  return *reinterpret_cast<const half8*>(Wsb + byte);
}

// ---------------- weight transpose+cast ----------------
__global__ __launch_bounds__(256) void transpose_w_kernel(
    const float* __restrict__ src, f16* __restrict__ dst, int K, int C, int total) {
  int idx = blockIdx.x * 256 + threadIdx.x;
  if (idx >= total) return;
  int kc = K * C;
  int m = idx / kc;
  int rem = idx - m * kc;
  int c = rem / K;
  int k = rem - c * K;
  dst[idx] = (f16)src[(size_t)m * kc + (size_t)k * C + c];
}

__global__ __launch_bounds__(256) void transpose3_kernel(
    const float* __restrict__ s0, const float* __restrict__ s1,
    const float* __restrict__ s2, f16* __restrict__ d0,
    f16* __restrict__ d1, f16* __restrict__ d2) {
  int idx = blockIdx.x * 256 + threadIdx.x;
  const int per = 3 * 128 * 128;
  int which = idx / per;
  if (which >= 3) return;
  int rem = idx - which * per;
  const float* s = (which == 0) ? s0 : (which == 1) ? s1 : s2;
  f16* d = (which == 0) ? d0 : (which == 1) ? d1 : d2;
  int m = rem >> 14;
  int r2 = rem & 16383;
  int c = r2 >> 7, k = r2 & 127;
  d[rem] = (f16)s[m * 16384 + k * 128 + c];
}

// ---------------- merged: encoder + degree count (independent work) ---------
// blocks [0, nEncBlk): h = tanh(x@enc_W+enc_b); blocks [nEncBlk, ...): count.
__global__ __launch_bounds__(512) void enc_count_kernel(
    const float* __restrict__ x, const float* __restrict__ W,
    const float* __restrict__ b, f16* __restrict__ h, int n, int nEncBlk,
    const int* __restrict__ dst, int* __restrict__ deg, int E) {
  if ((int)blockIdx.x < nEncBlk) {
    int idx = blockIdx.x * 512 + threadIdx.x;
    if (idx >= n * ED) return;
    int i = idx >> 7, c = idx & 127;
    float v = x[i * 2 + 0] * W[c] + x[i * 2 + 1] * W[ED + c] + b[c];
    h[idx] = (f16)tanh_fast(v);
  } else {
    int e = (blockIdx.x - nEncBlk) * 512 + threadIdx.x;
    if (e < E) atomicAdd(&deg[dst[e]], 1);
  }
}

// ---------------- scan ----------------
__global__ __launch_bounds__(1024) void scan_kernel(
    const int* __restrict__ deg, int* __restrict__ offs,
    int* __restrict__ cursor, int n) {
  __shared__ int wsum[16];
  __shared__ int carry_s;
  const int tid = threadIdx.x;
  const int lane = tid & 63;
  const int wid = tid >> 6;
  if (tid == 0) carry_s = 0;
  __syncthreads();
  for (int base = 0; base < n; base += 1024) {
    const int i = base + tid;
    const int v = (i < n) ? deg[i] : 0;
    int x = v;
    #pragma unroll
    for (int d = 1; d < 64; d <<= 1) {
      int t = __shfl_up(x, d, 64);
      if (lane >= d) x += t;
    }
    if (lane == 63) wsum[wid] = x;
    __syncthreads();
    int wbase = 0, total = 0;
    #pragma unroll
    for (int w = 0; w < 16; ++w) {
      int s = wsum[w];
      if (w < wid) wbase += s;
      total += s;
    }
    const int carry = carry_s;
    if (i < n) {
      const int excl = carry + wbase + x - v;
      offs[i] = excl;
      cursor[i] = excl;
    }
    __syncthreads();
    if (tid == 0) carry_s = carry + total;
    __syncthreads();
  }
  if (tid == 0) offs[n] = carry_s;
}

// ---------------- merged: MGV layer 0 + CSR scatter (independent work) ------
// blocks [0, gemmBlk): MGV0 (needs h, weights); blocks [gemmBlk, ...): scatter
// (needs cursor from scan). Overlaps the 55us write-bound scatter under MGV0.
__global__ __launch_bounds__(512, 4) void mgv_scatter_kernel(
    const f16* __restrict__ h,
    const f16* __restrict__ mWt, const float* __restrict__ mb,
    const f16* __restrict__ gWt, const float* __restrict__ gb,
    const f16* __restrict__ aWt, const float* __restrict__ ab,
    f16* __restrict__ P, int n, int gemmBlk,
    const int* __restrict__ src, const int* __restrict__ dst,
    int* __restrict__ cursor, int* __restrict__ ssrc, int E) {
  __shared__ f16 Ws[128 * 128];
  __shared__ f16 Ss[128 * 128];

  if ((int)blockIdx.x >= gemmBlk) {
    int e = (blockIdx.x - gemmBlk) * 512 + threadIdx.x;
    if (e < E) {
      int d = dst[e];
      int pos = atomicAdd(&cursor[d], 1);
      ssrc[pos] = src[e];
    }
    return;
  }

  char* Wsb = reinterpret_cast<char*>(Ws);
  char* Sb = reinterpret_cast<char*>(Ss);
  const int tid = threadIdx.x;
  const int w = tid >> 6, lane = tid & 63;
  const int lr = lane & 15, lg = lane >> 4;
  const int r0 = blockIdx.x * 128 + w * 16;

  half8 a[4];
  {
    int rr = r0 + lr;
    if (rr >= n) rr = n - 1;
    const f16* ap = h + (size_t)rr * ED + lg * 8;
    #pragma unroll
    for (int kt = 0; kt < 4; ++kt)
      a[kt] = *reinterpret_cast<const half8*>(ap + kt * 32);
  }

  // ---- phase M ----
  stage256<512, 32768>((const char*)mWt, Wsb, tid);
  __syncthreads();
  #pragma unroll
  for (int t = 0; t < 8; ++t) {
    f32x4 acc = {0.f, 0.f, 0.f, 0.f};
    int col = t * 16 + lr;
    #pragma unroll
    for (int kt = 0; kt < 4; ++kt)
      acc = __builtin_amdgcn_mfma_f32_16x16x32_f16(a[kt], read_w(Wsb, col, lg * 16 + kt * 64), acc, 0, 0, 0);
    float bias = mb[col];
    #pragma unroll
    for (int j = 0; j < 4; ++j) {
      int srow = w * 16 + lg * 4 + j;
      int byte = srow * 256 + (((col * 2) ^ ((srow & 7) << 4)));
      *reinterpret_cast<f16*>(Sb + byte) = (f16)tanh_fast(acc[j] + bias);
    }
  }
  half8 ma[4];
  {
    int lrow = w * 16 + lr;
    #pragma unroll
    for (int kt = 0; kt < 4; ++kt) {
      int byte = lrow * 256 + ((lg * 16 + kt * 64) ^ ((lrow & 7) << 4));
      ma[kt] = *reinterpret_cast<const half8*>(Sb + byte);
    }
  }
  __syncthreads();

  // ---- phase G ----
  stage256<512, 32768>((const char*)gWt, Wsb, tid);
  __syncthreads();
  #pragma unroll
  for (int t = 0; t < 8; ++t) {
    f32x4 acc = {0.f, 0.f, 0.f, 0.f};
    int col = t * 16 + lr;
    #pragma unroll
    for (int kt = 0; kt < 4; ++kt)
      acc = __builtin_amdgcn_mfma_f32_16x16x32_f16(ma[kt], read_w(Wsb, col, lg * 16 + kt * 64), acc, 0, 0, 0);
    float bias = gb[col];
    #pragma unroll
    for (int j = 0; j < 4; ++j) {
      int grow = r0 + lg * 4 + j;
      if (grow < n)
        P[(size_t)grow * PROW + col] = (f16)fminf(__expf(acc[j] + bias), 60000.f);
    }
  }
  __syncthreads();

  // ---- phase V ----
  stage256<512, 32768>((const char*)aWt, Wsb, tid);
  __syncthreads();
  #pragma unroll
  for (int t = 0; t < 8; ++t) {
    f32x4 acc = {0.f, 0.f, 0.f, 0.f};
    int col = t * 16 + lr;
    #pragma unroll
    for (int kt = 0; kt < 4; ++kt)
      acc = __builtin_amdgcn_mfma_f32_16x16x32_f16(ma[kt], read_w(Wsb, col, lg * 16 + kt * 64), acc, 0, 0, 0);
    float bias = ab[col];
    #pragma unroll
    for (int j = 0; j < 4; ++j) {
      int grow = r0 + lg * 4 + j;
      if (grow < n) {
        float wld = (float)P[(size_t)grow * PROW + col];
        P[(size_t)grow * PROW + 128 + col] = (f16)(wld * tanh_fast(acc[j] + bias));
      }
    }
  }
}

// ---------------- fused upd + MGV (layers 1,2) ----------------
__global__ __launch_bounds__(512, 4) void updmgv_kernel(
    const f16* __restrict__ h, const f16* __restrict__ ag,
    const f16* __restrict__ uWt, const float* __restrict__ ub,
    const f16* __restrict__ mWt, const float* __restrict__ mb,
    const f16* __restrict__ gWt, const float* __restrict__ gb,
    const f16* __restrict__ aWt, const float* __restrict__ ab,
    f16* __restrict__ hout, f16* __restrict__ P, int n) {
  __shared__ f16 Ws[128 * 128];
  __shared__ f16 Ss[128 * 128];
  char* Wsb = reinterpret_cast<char*>(Ws);
  char* Sb = reinterpret_cast<char*>(Ss);
  const int tid = threadIdx.x;
  const int w = tid >> 6, lane = tid & 63;
  const int lr = lane & 15, lg = lane >> 4;
  const int r0 = blockIdx.x * 128 + w * 16;

  half8 ah[4], aa[4];
  {
    int rr = r0 + lr;
    if (rr >= n) rr = n - 1;
    const f16* ap = h + (size_t)rr * ED + lg * 8;
    const f16* bp = ag + (size_t)rr * ED + lg * 8;
    #pragma unroll
    for (int kt = 0; kt < 4; ++kt) {
      ah[kt] = *reinterpret_cast<const half8*>(ap + kt * 32);
      aa[kt] = *reinterpret_cast<const half8*>(bp + kt * 32);
    }
  }

  // ---- phase U (column halves) ----
  #pragma unroll
  for (int half = 0; half < 2; ++half) {
    __syncthreads();
    stage512<512>((const char*)uWt + (size_t)half * 64 * 512, Wsb, tid);
    __syncthreads();
    #pragma unroll
    for (int t = 0; t < 4; ++t) {
      int colL = t * 16 + lr;
      int col = half * 64 + colL;
      f32x4 acc = {0.f, 0.f, 0.f, 0.f};
      #pragma unroll
      for (int kt = 0; kt < 4; ++kt)
        acc = __builtin_amdgcn_mfma_f32_16x16x32_f16(ah[kt], read_w512(Wsb, colL, lg * 16 + kt * 64), acc, 0, 0, 0);
      #pragma unroll
      for (int kt = 0; kt < 4; ++kt)
        acc = __builtin_amdgcn_mfma_f32_16x16x32_f16(aa[kt], read_w512(Wsb, colL, 256 + lg * 16 + kt * 64), acc, 0, 0, 0);
      float bias = ub[col];
      #pragma unroll
      for (int j = 0; j < 4; ++j) {
        f16 hv = (f16)tanh_fast(acc[j] + bias);
        int srow = w * 16 + lg * 4 + j;
        int byte = srow * 256 + (((col * 2) ^ ((srow & 7) << 4)));
        *reinterpret_cast<f16*>(Sb + byte) = hv;
        int grow = r0 + lg * 4 + j;
        if (grow < n) hout[(size_t)grow * ED + col] = hv;
      }
    }
  }
  half8 ha[4];
  {
    int lrow = w * 16 + lr;
    #pragma unroll
    for (int kt = 0; kt < 4; ++kt) {
      int byte = lrow * 256 + ((lg * 16 + kt * 64) ^ ((lrow & 7) << 4));
      ha[kt] = *reinterpret_cast<const half8*>(Sb + byte);
    }
  }
  __syncthreads();

  // ---- phase M ----
  stage256<512, 32768>((const char*)mWt, Wsb, tid);
  __syncthreads();
  #pragma unroll
  for (int t = 0; t < 8; ++t) {
    f32x4 acc = {0.f, 0.f, 0.f, 0.f};
    int col = t * 16 + lr;
    #pragma unroll
    for (int kt = 0; kt < 4; ++kt)
      acc = __builtin_amdgcn_mfma_f32_16x16x32_f16(ha[kt], read_w(Wsb, col, lg * 16 + kt * 64), acc, 0, 0, 0);
    float bias = mb[col];
    #pragma unroll
    for (int j = 0; j < 4; ++j) {
      int srow = w * 16 + lg * 4 + j;
      int byte = srow * 256 + (((col * 2) ^ ((srow & 7) << 4)));
      *reinterpret_cast<f16*>(Sb + byte) = (f16)tanh_fast(acc[j] + bias);
    }
  }
  half8 ma[4];
  {
    int lrow = w * 16 + lr;
    #pragma unroll
    for (int kt = 0; kt < 4; ++kt) {
      int byte = lrow * 256 + ((lg * 16 + kt * 64) ^ ((lrow & 7) << 4));
      ma[kt] = *reinterpret_cast<const half8*>(Sb + byte);
    }
  }
  __syncthreads();

  // ---- phase G ----
  stage256<512, 32768>((const char*)gWt, Wsb, tid);
  __syncthreads();
  #pragma unroll
  for (int t = 0; t < 8; ++t) {
    f32x4 acc = {0.f, 0.f, 0.f, 0.f};
    int col = t * 16 + lr;
    #pragma unroll
    for (int kt = 0; kt < 4; ++kt)
      acc = __builtin_amdgcn_mfma_f32_16x16x32_f16(ma[kt], read_w(Wsb, col, lg * 16 + kt * 64), acc, 0, 0, 0);
    float bias = gb[col];
    #pragma unroll
    for (int j = 0; j < 4; ++j) {
      int grow = r0 + lg * 4 + j;
      if (grow < n)
        P[(size_t)grow * PROW + col] = (f16)fminf(__expf(acc[j] + bias), 60000.f);
    }
  }
  __syncthreads();

  // ---- phase V ----
  stage256<512, 32768>((const char*)aWt, Wsb, tid);
  __syncthreads();
  #pragma unroll
  for (int t = 0; t < 8; ++t) {
    f32x4 acc = {0.f, 0.f, 0.f, 0.f};
    int col = t * 16 + lr;
    #pragma unroll
    for (int kt = 0; kt < 4; ++kt)
      acc = __builtin_amdgcn_mfma_f32_16x16x32_f16(ma[kt], read_w(Wsb, col, lg * 16 + kt * 64), acc, 0, 0, 0);
    float bias = ab[col];
    #pragma unroll
    for (int j = 0; j < 4; ++j) {
      int grow = r0 + lg * 4 + j;
      if (grow < n) {
        float wld = (float)P[(size_t)grow * PROW + col];
        P[(size_t)grow * PROW + 128 + col] = (f16)(wld * tanh_fast(acc[j] + bias));
      }
    }
  }
}

// ---------------- fused upd + decoder (layer 2 end) ----------------
__global__ __launch_bounds__(512, 4) void upddec_kernel(
    const f16* __restrict__ h, const f16* __restrict__ ag,
    const f16* __restrict__ uWt, const float* __restrict__ ub,
    const f16* __restrict__ d1Wt, const float* __restrict__ d1b,
    const float* __restrict__ d2W, const float* __restrict__ d2b,
    float* __restrict__ out, int n) {
  __shared__ f16 Ws[128 * 128];
  __shared__ f16 Ss[128 * 128];
  char* Wsb = reinterpret_cast<char*>(Ws);
  char* Sb = reinterpret_cast<char*>(Ss);
  const int tid = threadIdx.x;
  const int w = tid >> 6, lane = tid & 63;
  const int lr = lane & 15, lg = lane >> 4;
  const int r0 = blockIdx.x * 128 + w * 16;

  half8 ah[4], aa[4];
  {
    int rr = r0 + lr;
    if (rr >= n) rr = n - 1;
    const f16* ap = h + (size_t)rr * ED + lg * 8;
    const f16* bp = ag + (size_t)rr * ED + lg * 8;
    #pragma unroll
    for (int kt = 0; kt < 4; ++kt) {
      ah[kt] = *reinterpret_cast<const half8*>(ap + kt * 32);
      aa[kt] = *reinterpret_cast<const half8*>(bp + kt * 32);
    }
  }

  // ---- phase U (column halves) -> stripe only ----
  #pragma unroll
  for (int half = 0; half < 2; ++half) {
    __syncthreads();
    stage512<512>((const char*)uWt + (size_t)half * 64 * 512, Wsb, tid);
    __syncthreads();
    #pragma unroll
    for (int t = 0; t < 4; ++t) {
      int colL = t * 16 + lr;
      int col = half * 64 + colL;
      f32x4 acc = {0.f, 0.f, 0.f, 0.f};
      #pragma unroll
      for (int kt = 0; kt < 4; ++kt)
        acc = __builtin_amdgcn_mfma_f32_16x16x32_f16(ah[kt], read_w512(Wsb, colL, lg * 16 + kt * 64), acc, 0, 0, 0);
      #pragma unroll
      for (int kt = 0; kt < 4; ++kt)
        acc = __builtin_amdgcn_mfma_f32_16x16x32_f16(aa[kt], read_w512(Wsb, colL, 256 + lg * 16 + kt * 64), acc, 0, 0, 0);
      float bias = ub[col];
      #pragma unroll
      for (int j = 0; j < 4; ++j) {
        int srow = w * 16 + lg * 4 + j;
        int byte = srow * 256 + (((col * 2) ^ ((srow & 7) << 4)));
        *reinterpret_cast<f16*>(Sb + byte) = (f16)tanh_fast(acc[j] + bias);
      }
    }
  }
  half8 ha[4];
  {
    int lrow = w * 16 + lr;
    #pragma unroll
    for (int kt = 0; kt < 4; ++kt) {
      int byte = lrow * 256 + ((lg * 16 + kt * 64) ^ ((lrow & 7) << 4));
      ha[kt] = *reinterpret_cast<const half8*>(Sb + byte);
    }
  }
  __syncthreads();

  // ---- decoder ----
  stage256<512, 16384>((const char*)d1Wt, Wsb, tid);
  __syncthreads();
  float rowsum[4] = {0.f, 0.f, 0.f, 0.f};
  #pragma unroll
  for (int t = 0; t < 4; ++t) {
    f32x4 acc = {0.f, 0.f, 0.f, 0.f};
    int col = t * 16 + lr;
    #pragma unroll
    for (int kt = 0; kt < 4; ++kt)
      acc = __builtin_amdgcn_mfma_f32_16x16x32_f16(ha[kt], read_w(Wsb, col, lg * 16 + kt * 64), acc, 0, 0, 0);
    float b1 = d1b[col], w2 = d2W[col];
    #pragma unroll
    for (int j = 0; j < 4; ++j) rowsum[j] += tanh_fast(acc[j] + b1) * w2;
  }
  #pragma unroll
  for (int d = 1; d < 16; d <<= 1) {
    #pragma unroll
    for (int j = 0; j < 4; ++j) rowsum[j] += __shfl_xor(rowsum[j], d, 64);
  }
  if (lr == 0) {
    #pragma unroll
    for (int j = 0; j < 4; ++j) {
      int grow = r0 + lg * 4 + j;
      if (grow < n) out[grow] = rowsum[j] + d2b[0];
    }
  }
}

// ---------------- edge aggregation: one wave per dst node (proven floor) ----
__global__ __launch_bounds__(256) void edge_aggr_kernel(
    const int* __restrict__ offs, const int* __restrict__ ssrc,
    const f16* __restrict__ P, f16* __restrict__ aggr, int n) {
  int i = blockIdx.x * 4 + (threadIdx.x >> 6);
  if (i >= n) return;
  int lane = threadIdx.x & 63;
  int s0 = offs[i], s1 = offs[i + 1];
  const char* Pb = reinterpret_cast<const char*>(P);

  float4 acc = {0.f, 0.f, 0.f, 0.f};
  #pragma unroll 4
  for (int e = s0; e < s1; ++e) {
    int sn = ssrc[e];
    half4 x = *reinterpret_cast<const half4*>(Pb + (size_t)sn * 512 + lane * 8);
    acc.x += (float)x.x;
    acc.y += (float)x.y;
    acc.z += (float)x.z;
    acc.w += (float)x.w;
  }
  float px = __shfl(acc.x, lane ^ 32, 64);
  float py = __shfl(acc.y, lane ^ 32, 64);
  float pz = __shfl(acc.z, lane ^ 32, 64);
  float pw = __shfl(acc.w, lane ^ 32, 64);
  if (lane >= 32) {
    half4 o;
    o.x = (f16)(acc.x / (px + 1e-16f));
    o.y = (f16)(acc.y / (py + 1e-16f));
    o.z = (f16)(acc.z / (pz + 1e-16f));
    o.w = (f16)(acc.w / (pw + 1e-16f));
    *reinterpret_cast<half4*>(
        reinterpret_cast<char*>(aggr) + (size_t)i * 256 + (size_t)(lane - 32) * 8) = o;
  }
}

// ---------------- host ----------------
extern "C" void kernel_launch(void* const* d_in, const int* in_sizes, int n_in,
                              void* d_out, int out_size, void* d_ws, size_t ws_size,
                              hipStream_t stream) {
  const float* node_feature = (const float*)d_in[0];
  const int*   edge_index   = (const int*)d_in[1];
  const float* enc_W  = (const float*)d_in[3];
  const float* enc_b  = (const float*)d_in[4];
  const float* gate_W = (const float*)d_in[5];
  const float* gate_b = (const float*)d_in[6];
  const float* att_W  = (const float*)d_in[7];
  const float* att_b  = (const float*)d_in[8];
  const float* msg_W  = (const float*)d_in[9];
  const float* msg_b  = (const float*)d_in[10];
  const float* upd_W  = (const float*)d_in[11];
  const float* upd_b  = (const float*)d_in[12];
  const float* dec1_W = (const float*)d_in[13];
  const float* dec1_b = (const float*)d_in[14];
  const float* dec2_W = (const float*)d_in[15];
  const float* dec2_b = (const float*)d_in[16];

  const int n = in_sizes[0] / 2;   // 50000
  const int E = in_sizes[1] / 2;   // 800000
  const int* src = edge_index;
  const int* dst = edge_index + E;

  char* ws = (char*)d_ws;
  size_t off = 0;
  auto alloc = [&](size_t bytes) -> void* {
    void* p = ws + off;
    off += (bytes + 255) & ~(size_t)255;
    return p;
  };
  f16* hA   = (f16*)alloc((size_t)n * ED * 2);
  f16* hB   = (f16*)alloc((size_t)n * ED * 2);
  f16* P    = (f16*)alloc((size_t)n * PROW * 2);
  f16* aggr = (f16*)alloc((size_t)n * ED * 2);
  int* deg    = (int*)alloc((size_t)n * 4);
  int* offs   = (int*)alloc((size_t)(n + 1) * 4);
  int* cursor = (int*)alloc((size_t)n * 4);
  int* ssrc   = (int*)alloc((size_t)E * 4);
  f16* msgT  = (f16*)alloc((size_t)3 * ED * ED * 2);
  f16* gateT = (f16*)alloc((size_t)3 * ED * ED * 2);
  f16* attT  = (f16*)alloc((size_t)3 * ED * ED * 2);
  f16* updT  = (f16*)alloc((size_t)3 * ED * 2 * ED * 2);
  f16* dec1T = (f16*)alloc((size_t)ED * 64 * 2);

  // weight prep (once per call)
  {
    int tot3 = 3 * 3 * ED * ED;
    transpose3_kernel<<<(tot3 + 255) / 256, 256, 0, stream>>>(
        msg_W, gate_W, att_W, msgT, gateT, attT);
    int totu = 3 * 2 * ED * ED;
    transpose_w_kernel<<<(totu + 255) / 256, 256, 0, stream>>>(
        upd_W, updT, 2 * ED, ED, totu);
    int totd = ED * 64;
    transpose_w_kernel<<<(totd + 255) / 256, 256, 0, stream>>>(
        dec1_W, dec1T, ED, 64, totd);
  }

  hipMemsetAsync(deg, 0, (size_t)n * 4, stream);

  // merged encoder + degree count
  const int nEncBlk = ((size_t)n * ED + 511) / 512;
  const int nCntBlk = (E + 511) / 512;
  enc_count_kernel<<<nEncBlk + nCntBlk, 512, 0, stream>>>(
      node_feature, enc_W, enc_b, hA, n, nEncBlk, dst, deg, E);

  scan_kernel<<<1, 1024, 0, stream>>>(deg, offs, cursor, n);

  const int gemm_grid = (n + 127) / 128;   // 391
  const int aggr_grid = (n + 3) / 4;
  const int nSctBlk = (E + 511) / 512;

  // merged MGV layer 0 + scatter (overlapped)
  mgv_scatter_kernel<<<gemm_grid + nSctBlk, 512, 0, stream>>>(
      hA, msgT, msg_b, gateT, gate_b, attT, att_b, P, n, gemm_grid,
      src, dst, cursor, ssrc, E);
  edge_aggr_kernel<<<aggr_grid, 256, 0, stream>>>(offs, ssrc, P, aggr, n);

  // upd0 + MGV1
  updmgv_kernel<<<gemm_grid, 512, 0, stream>>>(
      hA, aggr, updT, upd_b,
      msgT + (size_t)1 * ED * ED, msg_b + ED,
      gateT + (size_t)1 * ED * ED, gate_b + ED,
      attT + (size_t)1 * ED * ED, att_b + ED,
      hB, P, n);
  edge_aggr_kernel<<<aggr_grid, 256, 0, stream>>>(offs, ssrc, P, aggr, n);

  // upd1 + MGV2
  updmgv_kernel<<<gemm_grid, 512, 0, stream>>>(
      hB, aggr, updT + (size_t)1 * 2 * ED * ED, upd_b + ED,
      msgT + (size_t)2 * ED * ED, msg_b + 2 * ED,
      gateT + (size_t)2 * ED * ED, gate_b + 2 * ED,
      attT + (size_t)2 * ED * ED, att_b + 2 * ED,
      hA, P, n);
  edge_aggr_kernel<<<aggr_grid, 256, 0, stream>>>(offs, ssrc, P, aggr, n);

  // upd2 + decoder
  upddec_kernel<<<gemm_grid, 512, 0, stream>>>(
      hA, aggr, updT + (size_t)2 * 2 * ED * ED, upd_b + 2 * ED,
      dec1T, dec1_b, dec2_W, dec2_b, (float*)d_out, n);
}